// Round 1
// baseline (534.276 us; speedup 1.0000x reference)
//
#include <hip/hip_runtime.h>
#include <hip/hip_bf16.h>
#include <math.h>

__device__ __forceinline__ float lrelu(float x) { return x >= 0.f ? x : 0.2f * x; }

// ---------------- CSR build (sort edges by dst) ----------------
__global__ void degree_kernel(const int* __restrict__ dst, int* __restrict__ deg, int E) {
    int e = blockIdx.x * blockDim.x + threadIdx.x;
    if (e < E) atomicAdd(&deg[dst[e]], 1);
}

__global__ __launch_bounds__(1024) void scan_kernel(const int* __restrict__ deg,
                                                    int* __restrict__ off, int n) {
    __shared__ int wsum[16];
    __shared__ int s_carry;
    int t = threadIdx.x, lane = t & 63, w = t >> 6;
    if (t == 0) s_carry = 0;
    __syncthreads();
    for (int base = 0; base < n; base += 1024) {
        int i = base + t;
        int v = (i < n) ? deg[i] : 0;
        int x = v;
        #pragma unroll
        for (int d = 1; d < 64; d <<= 1) { int y = __shfl_up(x, d); if (lane >= d) x += y; }
        if (lane == 63) wsum[w] = x;
        __syncthreads();
        if (w == 0 && lane < 16) {
            int y = wsum[lane];
            #pragma unroll
            for (int d = 1; d < 16; d <<= 1) { int z = __shfl_up(y, d); if (lane >= d) y += z; }
            wsum[lane] = y;
        }
        __syncthreads();
        int wave_off = (w == 0) ? 0 : wsum[w - 1];
        if (i < n) off[i] = s_carry + wave_off + (x - v);
        __syncthreads();
        if (t == 0) s_carry += wsum[15];
        __syncthreads();
    }
    if (threadIdx.x == 0) off[n] = s_carry;
}

__global__ void scatter_kernel(const int* __restrict__ src, const int* __restrict__ dst,
                               const int* __restrict__ off, int* __restrict__ cursor,
                               int* __restrict__ ssrc, int E) {
    int e = blockIdx.x * blockDim.x + threadIdx.x;
    if (e < E) {
        int d = dst[e];
        int pos = off[d] + atomicAdd(&cursor[d], 1);
        ssrc[pos] = src[e];
    }
}

// ---------------- dual GEMM: Cl = A@Wl, Cr = A@Wr  (K=128) ----------------
template <int M>
__global__ __launch_bounds__(256) void dual_gemm_kernel(
    const float* __restrict__ A, const float* __restrict__ Wl, const float* __restrict__ Wr,
    float* __restrict__ Cl, float* __restrict__ Cr, int nrows) {
    constexpr int K = 128;
    constexpr int ROWS = 32;
    constexpr int CPT = (2 * M) / 32;  // cols per thread: 8 (M=128) or 4 (M=64)
    constexpr int LDA = K + 4;         // pad: bank-conflict-free column reads, 16B aligned
    __shared__ float As[ROWS * LDA];
    int t = threadIdx.x;
    int row_base = blockIdx.x * ROWS;
    for (int idx = t * 4; idx < ROWS * K; idx += 256 * 4) {
        int r = idx >> 7;
        int k = idx & 127;
        float4 v = make_float4(0.f, 0.f, 0.f, 0.f);
        if (row_base + r < nrows)
            v = *reinterpret_cast<const float4*>(&A[(size_t)(row_base + r) * K + k]);
        *reinterpret_cast<float4*>(&As[r * LDA + k]) = v;
    }
    __syncthreads();
    int cg = t & 31;
    int rg = t >> 5;
    int g0 = cg * CPT;
    const float* W = (g0 < M) ? Wl : Wr;
    float* C = (g0 < M) ? Cl : Cr;
    int c0 = (g0 < M) ? g0 : g0 - M;
    int r0 = rg * 4;
    float acc[4][CPT];
    #pragma unroll
    for (int r = 0; r < 4; ++r)
        #pragma unroll
        for (int j = 0; j < CPT; ++j) acc[r][j] = 0.f;
    for (int k = 0; k < K; ++k) {
        float a0 = As[(r0 + 0) * LDA + k];
        float a1 = As[(r0 + 1) * LDA + k];
        float a2 = As[(r0 + 2) * LDA + k];
        float a3 = As[(r0 + 3) * LDA + k];
        #pragma unroll
        for (int j = 0; j < CPT; ++j) {
            float wv = W[k * M + c0 + j];
            acc[0][j] += a0 * wv;
            acc[1][j] += a1 * wv;
            acc[2][j] += a2 * wv;
            acc[3][j] += a3 * wv;
        }
    }
    #pragma unroll
    for (int r = 0; r < 4; ++r) {
        int row = row_base + r0 + r;
        if (row < nrows) {
            #pragma unroll
            for (int j = 0; j < CPT; j += 4) {
                float4 v = make_float4(acc[r][j], acc[r][j + 1], acc[r][j + 2], acc[r][j + 3]);
                *reinterpret_cast<float4*>(&C[(size_t)row * M + c0 + j]) = v;
            }
        }
    }
}

// ---------------- GAT layer 1: H=8, C=16, F=128; fused bias+LN+ELU ----------------
__global__ __launch_bounds__(256) void gat1_kernel(
    const float* __restrict__ xl, const float* __restrict__ xr,
    const int* __restrict__ off, const int* __restrict__ ssrc,
    const float* __restrict__ att, const float* __restrict__ bias,
    const float* __restrict__ gamma, const float* __restrict__ beta,
    float* __restrict__ out, int n) {
    int lane = threadIdx.x & 63;
    int node = blockIdx.x * 4 + (threadIdx.x >> 6);
    if (node >= n) return;
    int i0 = lane, i1 = 64 + lane;  // (h,c) flat: h = hq and hq+4, c = lane&15
    float xr0 = xr[(size_t)node * 128 + i0], xr1 = xr[(size_t)node * 128 + i1];
    float at0 = att[i0], at1 = att[i1];
    float m0 = -INFINITY, m1 = -INFINITY;
    float s0 = 0.f, s1 = 0.f, acc0 = 0.f, acc1 = 0.f;
    int beg = off[node], end = off[node + 1];
    for (int i = beg; i < end; ++i) {
        int src = ssrc[i];
        float xl0 = xl[(size_t)src * 128 + i0];
        float xl1v = xl[(size_t)src * 128 + i1];
        float p0 = at0 * lrelu(xl0 + xr0);
        float p1 = at1 * lrelu(xl1v + xr1);
        #pragma unroll
        for (int d = 1; d < 16; d <<= 1) {  // reduce over c (16 lanes per head)
            p0 += __shfl_xor(p0, d);
            p1 += __shfl_xor(p1, d);
        }
        // online softmax per head
        float mn0 = fmaxf(m0, p0);
        float sc0 = __expf(m0 - mn0);
        float w0 = __expf(p0 - mn0);
        s0 = s0 * sc0 + w0;
        acc0 = acc0 * sc0 + w0 * xl0;
        m0 = mn0;
        float mn1 = fmaxf(m1, p1);
        float sc1 = __expf(m1 - mn1);
        float w1 = __expf(p1 - mn1);
        s1 = s1 * sc1 + w1;
        acc1 = acc1 * sc1 + w1 * xl1v;
        m1 = mn1;
    }
    float o0 = acc0 / (s0 + 1e-16f) + bias[i0];
    float o1 = acc1 / (s1 + 1e-16f) + bias[i1];
    // LayerNorm over 128 + ELU
    float tsum = o0 + o1;
    #pragma unroll
    for (int d = 1; d < 64; d <<= 1) tsum += __shfl_xor(tsum, d);
    float mu = tsum * (1.f / 128.f);
    float d0 = o0 - mu, d1 = o1 - mu;
    float vsum = d0 * d0 + d1 * d1;
    #pragma unroll
    for (int d = 1; d < 64; d <<= 1) vsum += __shfl_xor(vsum, d);
    float rs = rsqrtf(vsum * (1.f / 128.f) + 1e-5f);
    float y0 = d0 * rs * gamma[i0] + beta[i0];
    float y1 = d1 * rs * gamma[i1] + beta[i1];
    y0 = y0 > 0.f ? y0 : expm1f(y0);
    y1 = y1 > 0.f ? y1 : expm1f(y1);
    out[(size_t)node * 128 + i0] = y0;
    out[(size_t)node * 128 + i1] = y1;
}

// ---------------- GAT layer 2: H=1, C=64; fused bias+LN -> d_out ----------------
__global__ __launch_bounds__(256) void gat2_kernel(
    const float* __restrict__ xl, const float* __restrict__ xr,
    const int* __restrict__ off, const int* __restrict__ ssrc,
    const float* __restrict__ att, const float* __restrict__ bias,
    const float* __restrict__ gamma, const float* __restrict__ beta,
    float* __restrict__ out, int n) {
    int lane = threadIdx.x & 63;
    int node = blockIdx.x * 4 + (threadIdx.x >> 6);
    if (node >= n) return;
    float xrv = xr[(size_t)node * 64 + lane];
    float atv = att[lane];
    float m = -INFINITY, s = 0.f, acc = 0.f;
    int beg = off[node], end = off[node + 1];
    for (int i = beg; i < end; ++i) {
        int src = ssrc[i];
        float xlv = xl[(size_t)src * 64 + lane];
        float p = atv * lrelu(xlv + xrv);
        #pragma unroll
        for (int d = 1; d < 64; d <<= 1) p += __shfl_xor(p, d);
        float mn = fmaxf(m, p);
        float sc = __expf(m - mn);
        float w = __expf(p - mn);
        s = s * sc + w;
        acc = acc * sc + w * xlv;
        m = mn;
    }
    float o = acc / (s + 1e-16f) + bias[lane];
    float tsum = o;
    #pragma unroll
    for (int d = 1; d < 64; d <<= 1) tsum += __shfl_xor(tsum, d);
    float mu = tsum * (1.f / 64.f);
    float dd = o - mu;
    float vsum = dd * dd;
    #pragma unroll
    for (int d = 1; d < 64; d <<= 1) vsum += __shfl_xor(vsum, d);
    float rs = rsqrtf(vsum * (1.f / 64.f) + 1e-5f);
    out[(size_t)node * 64 + lane] = dd * rs * gamma[lane] + beta[lane];
}

extern "C" void kernel_launch(void* const* d_in, const int* in_sizes, int n_in,
                              void* d_out, int out_size, void* d_ws, size_t ws_size,
                              hipStream_t stream) {
    const float* x = (const float*)d_in[0];
    const int* ei = (const int*)d_in[1];
    const float* Wl1 = (const float*)d_in[2];
    const float* Wr1 = (const float*)d_in[3];
    const float* att1 = (const float*)d_in[4];
    const float* bias1 = (const float*)d_in[5];
    const float* g1 = (const float*)d_in[6];
    const float* b1 = (const float*)d_in[7];
    const float* Wl2 = (const float*)d_in[8];
    const float* Wr2 = (const float*)d_in[9];
    const float* att2 = (const float*)d_in[10];
    const float* bias2 = (const float*)d_in[11];
    const float* g2 = (const float*)d_in[12];
    const float* b2 = (const float*)d_in[13];
    float* out = (float*)d_out;

    const int N = in_sizes[0] / 128;
    const int E = in_sizes[1] / 2;
    const int* src = ei;
    const int* dstp = ei + E;

    char* p = (char*)d_ws;
    auto alloc = [&](size_t bytes) -> char* {
        char* r = p;
        p += (bytes + 255) & ~(size_t)255;
        return r;
    };
    int* deg = (int*)alloc((size_t)N * 4);
    int* cursor = (int*)alloc((size_t)N * 4);
    int* off = (int*)alloc((size_t)(N + 1) * 4);
    int* ssrc = (int*)alloc((size_t)E * 4);
    float* bufA = (float*)alloc((size_t)N * 128 * 4);  // xl1, later xl2
    float* bufB = (float*)alloc((size_t)N * 128 * 4);  // xr1, later xr2
    float* h1 = (float*)alloc((size_t)N * 128 * 4);

    hipMemsetAsync(deg, 0, (size_t)N * 4, stream);
    hipMemsetAsync(cursor, 0, (size_t)N * 4, stream);
    degree_kernel<<<(E + 255) / 256, 256, 0, stream>>>(dstp, deg, E);
    scan_kernel<<<1, 1024, 0, stream>>>(deg, off, N);
    scatter_kernel<<<(E + 255) / 256, 256, 0, stream>>>(src, dstp, off, cursor, ssrc, E);

    dual_gemm_kernel<128><<<(N + 31) / 32, 256, 0, stream>>>(x, Wl1, Wr1, bufA, bufB, N);
    gat1_kernel<<<(N + 3) / 4, 256, 0, stream>>>(bufA, bufB, off, ssrc, att1, bias1, g1, b1, h1, N);
    dual_gemm_kernel<64><<<(N + 31) / 32, 256, 0, stream>>>(h1, Wl2, Wr2, bufA, bufB, N);
    gat2_kernel<<<(N + 3) / 4, 256, 0, stream>>>(bufA, bufB, off, ssrc, att2, bias2, g2, b2, out, N);
}

// Round 2
// 436.706 us; speedup vs baseline: 1.2234x; 1.2234x over previous
//
#include <hip/hip_runtime.h>
#include <hip/hip_bf16.h>
#include <math.h>

__device__ __forceinline__ float lrelu(float x) { return x >= 0.f ? x : 0.2f * x; }

// ---------------- CSR build (sort edges by dst) ----------------
__global__ void degree_kernel(const int* __restrict__ dst, int* __restrict__ deg, int E) {
    int e = blockIdx.x * blockDim.x + threadIdx.x;
    if (e < E) atomicAdd(&deg[dst[e]], 1);
}

__global__ __launch_bounds__(1024) void scan_kernel(const int* __restrict__ deg,
                                                    int* __restrict__ off, int n) {
    __shared__ int wsum[16];
    __shared__ int s_carry;
    int t = threadIdx.x, lane = t & 63, w = t >> 6;
    if (t == 0) s_carry = 0;
    __syncthreads();
    for (int base = 0; base < n; base += 4096) {
        int i = base + t * 4;
        int4 v = make_int4(0, 0, 0, 0);
        if (i + 3 < n) v = *reinterpret_cast<const int4*>(&deg[i]);
        else {
            if (i < n) v.x = deg[i];
            if (i + 1 < n) v.y = deg[i + 1];
            if (i + 2 < n) v.z = deg[i + 2];
        }
        int tsum = v.x + v.y + v.z + v.w;
        int x = tsum;
        #pragma unroll
        for (int d = 1; d < 64; d <<= 1) { int y = __shfl_up(x, d); if (lane >= d) x += y; }
        if (lane == 63) wsum[w] = x;
        __syncthreads();
        if (w == 0 && lane < 16) {
            int y = wsum[lane];
            #pragma unroll
            for (int d = 1; d < 16; d <<= 1) { int z = __shfl_up(y, d); if (lane >= d) y += z; }
            wsum[lane] = y;
        }
        __syncthreads();
        int excl = s_carry + ((w == 0) ? 0 : wsum[w - 1]) + (x - tsum);
        if (i < n) off[i] = excl;
        if (i + 1 < n) off[i + 1] = excl + v.x;
        if (i + 2 < n) off[i + 2] = excl + v.x + v.y;
        if (i + 3 < n) off[i + 3] = excl + v.x + v.y + v.z;
        __syncthreads();
        if (t == 0) s_carry += wsum[15];
        __syncthreads();
    }
    if (t == 0) off[n] = s_carry;
}

__global__ void scatter_kernel(const int* __restrict__ src, const int* __restrict__ dst,
                               const int* __restrict__ off, int* __restrict__ cursor,
                               int* __restrict__ ssrc, int E) {
    int e = blockIdx.x * blockDim.x + threadIdx.x;
    if (e < E) {
        int d = dst[e];
        int pos = off[d] + atomicAdd(&cursor[d], 1);
        ssrc[pos] = src[e];
    }
}

// ---------------- dual GEMM: Cl = A@Wl, Cr = A@Wr  (K=128, k-major LDS) ----------------
template <int M>
__global__ __launch_bounds__(256) void dual_gemm_kernel(
    const float* __restrict__ A, const float* __restrict__ Wl, const float* __restrict__ Wr,
    float* __restrict__ Cl, float* __restrict__ Cr, int nrows) {
    constexpr int K = 128;
    constexpr int ROWS = 32;
    constexpr int CPT = (2 * M) / 32;  // 8 (M=128) or 4 (M=64)
    constexpr int LDR = 36;            // k-major [K][ROWS+4]: float4-aligned, broadcast reads
    __shared__ float As[K * LDR];
    int t = threadIdx.x;
    int row_base = blockIdx.x * ROWS;
    // stage A transposed (k-major)
    for (int idx = t * 4; idx < ROWS * K; idx += 1024) {
        int r = idx >> 7;
        int k = idx & 127;
        float4 v = make_float4(0.f, 0.f, 0.f, 0.f);
        if (row_base + r < nrows)
            v = *reinterpret_cast<const float4*>(&A[(size_t)(row_base + r) * K + k]);
        As[(k + 0) * LDR + r] = v.x;
        As[(k + 1) * LDR + r] = v.y;
        As[(k + 2) * LDR + r] = v.z;
        As[(k + 3) * LDR + r] = v.w;
    }
    __syncthreads();
    int cg = t & 31;
    int rg = t >> 5;
    int g0 = cg * CPT;
    const float* W = (g0 < M) ? Wl : Wr;
    float* C = (g0 < M) ? Cl : Cr;
    int c0 = (g0 < M) ? g0 : g0 - M;
    int r0 = rg * 4;
    float acc[4][CPT];
    #pragma unroll
    for (int r = 0; r < 4; ++r)
        #pragma unroll
        for (int j = 0; j < CPT; ++j) acc[r][j] = 0.f;
    #pragma unroll 4
    for (int k = 0; k < K; ++k) {
        float4 a = *reinterpret_cast<const float4*>(&As[k * LDR + r0]);
        float wv[CPT];
        #pragma unroll
        for (int j = 0; j < CPT; j += 4) {
            float4 wq = *reinterpret_cast<const float4*>(&W[(size_t)k * M + c0 + j]);
            wv[j] = wq.x; wv[j + 1] = wq.y; wv[j + 2] = wq.z; wv[j + 3] = wq.w;
        }
        #pragma unroll
        for (int j = 0; j < CPT; ++j) {
            acc[0][j] += a.x * wv[j];
            acc[1][j] += a.y * wv[j];
            acc[2][j] += a.z * wv[j];
            acc[3][j] += a.w * wv[j];
        }
    }
    #pragma unroll
    for (int r = 0; r < 4; ++r) {
        int row = row_base + r0 + r;
        if (row < nrows) {
            #pragma unroll
            for (int j = 0; j < CPT; j += 4) {
                float4 v = make_float4(acc[r][j], acc[r][j + 1], acc[r][j + 2], acc[r][j + 3]);
                *reinterpret_cast<float4*>(&C[(size_t)row * M + c0 + j]) = v;
            }
        }
    }
}

// online-softmax update with deferred max (T13): m init -inf, rescale branch is rare
#define GAT_UPD(p, xv, m, s, acc)                                              \
    do {                                                                       \
        if (__builtin_expect((p) > (m) + 8.f, 0)) {                            \
            float sc_ = __expf((m) - (p));                                     \
            (s) *= sc_; (acc) *= sc_; (m) = (p);                               \
        }                                                                      \
        float w_ = __expf((p) - (m));                                          \
        (s) += w_; (acc) += w_ * (xv);                                         \
    } while (0)

// ---------------- GAT layer 1: H=8, C=16, F=128; fused bias+LN+ELU ----------------
__global__ __launch_bounds__(256) void gat1_kernel(
    const float* __restrict__ xl, const float* __restrict__ xr,
    const int* __restrict__ off, const int* __restrict__ ssrc,
    const float* __restrict__ att, const float* __restrict__ bias,
    const float* __restrict__ gamma, const float* __restrict__ beta,
    float* __restrict__ out, int n) {
    int lane = threadIdx.x & 63;
    int node = blockIdx.x * 4 + (threadIdx.x >> 6);
    if (node >= n) return;
    int i0 = lane, i1 = 64 + lane;
    float xr0 = xr[(size_t)node * 128 + i0], xr1 = xr[(size_t)node * 128 + i1];
    float at0 = att[i0], at1 = att[i1];
    float m0 = -INFINITY, m1 = -INFINITY;
    float s0 = 0.f, s1 = 0.f, acc0 = 0.f, acc1 = 0.f;
    int beg = off[node], end = off[node + 1];
    int i = beg;
    // unroll-4: four independent gather+reduce chains in flight
    for (; i + 4 <= end; i += 4) {
        int e0 = ssrc[i], e1 = ssrc[i + 1], e2 = ssrc[i + 2], e3 = ssrc[i + 3];
        const float* q0 = xl + (size_t)e0 * 128;
        const float* q1 = xl + (size_t)e1 * 128;
        const float* q2 = xl + (size_t)e2 * 128;
        const float* q3 = xl + (size_t)e3 * 128;
        float x00 = q0[i0], x01 = q0[i1];
        float x10 = q1[i0], x11 = q1[i1];
        float x20 = q2[i0], x21 = q2[i1];
        float x30 = q3[i0], x31 = q3[i1];
        float p00 = at0 * lrelu(x00 + xr0), p01 = at1 * lrelu(x01 + xr1);
        float p10 = at0 * lrelu(x10 + xr0), p11 = at1 * lrelu(x11 + xr1);
        float p20 = at0 * lrelu(x20 + xr0), p21 = at1 * lrelu(x21 + xr1);
        float p30 = at0 * lrelu(x30 + xr0), p31 = at1 * lrelu(x31 + xr1);
        #pragma unroll
        for (int d = 1; d < 16; d <<= 1) {
            p00 += __shfl_xor(p00, d); p01 += __shfl_xor(p01, d);
            p10 += __shfl_xor(p10, d); p11 += __shfl_xor(p11, d);
            p20 += __shfl_xor(p20, d); p21 += __shfl_xor(p21, d);
            p30 += __shfl_xor(p30, d); p31 += __shfl_xor(p31, d);
        }
        GAT_UPD(p00, x00, m0, s0, acc0); GAT_UPD(p01, x01, m1, s1, acc1);
        GAT_UPD(p10, x10, m0, s0, acc0); GAT_UPD(p11, x11, m1, s1, acc1);
        GAT_UPD(p20, x20, m0, s0, acc0); GAT_UPD(p21, x21, m1, s1, acc1);
        GAT_UPD(p30, x30, m0, s0, acc0); GAT_UPD(p31, x31, m1, s1, acc1);
    }
    for (; i < end; ++i) {
        int src = ssrc[i];
        float x0 = xl[(size_t)src * 128 + i0];
        float x1 = xl[(size_t)src * 128 + i1];
        float p0 = at0 * lrelu(x0 + xr0);
        float p1 = at1 * lrelu(x1 + xr1);
        #pragma unroll
        for (int d = 1; d < 16; d <<= 1) {
            p0 += __shfl_xor(p0, d);
            p1 += __shfl_xor(p1, d);
        }
        GAT_UPD(p0, x0, m0, s0, acc0);
        GAT_UPD(p1, x1, m1, s1, acc1);
    }
    float o0 = acc0 / (s0 + 1e-16f) + bias[i0];
    float o1 = acc1 / (s1 + 1e-16f) + bias[i1];
    // LayerNorm over 128 + ELU
    float tsum = o0 + o1;
    #pragma unroll
    for (int d = 1; d < 64; d <<= 1) tsum += __shfl_xor(tsum, d);
    float mu = tsum * (1.f / 128.f);
    float d0 = o0 - mu, d1 = o1 - mu;
    float vsum = d0 * d0 + d1 * d1;
    #pragma unroll
    for (int d = 1; d < 64; d <<= 1) vsum += __shfl_xor(vsum, d);
    float rs = rsqrtf(vsum * (1.f / 128.f) + 1e-5f);
    float y0 = d0 * rs * gamma[i0] + beta[i0];
    float y1 = d1 * rs * gamma[i1] + beta[i1];
    y0 = y0 > 0.f ? y0 : expm1f(y0);
    y1 = y1 > 0.f ? y1 : expm1f(y1);
    out[(size_t)node * 128 + i0] = y0;
    out[(size_t)node * 128 + i1] = y1;
}

// ---------------- GAT layer 2: H=1, C=64; fused bias+LN -> d_out ----------------
__global__ __launch_bounds__(256) void gat2_kernel(
    const float* __restrict__ xl, const float* __restrict__ xr,
    const int* __restrict__ off, const int* __restrict__ ssrc,
    const float* __restrict__ att, const float* __restrict__ bias,
    const float* __restrict__ gamma, const float* __restrict__ beta,
    float* __restrict__ out, int n) {
    int lane = threadIdx.x & 63;
    int node = blockIdx.x * 4 + (threadIdx.x >> 6);
    if (node >= n) return;
    float xrv = xr[(size_t)node * 64 + lane];
    float atv = att[lane];
    float m = -INFINITY, s = 0.f, acc = 0.f;
    int beg = off[node], end = off[node + 1];
    int i = beg;
    for (; i + 4 <= end; i += 4) {
        int e0 = ssrc[i], e1 = ssrc[i + 1], e2 = ssrc[i + 2], e3 = ssrc[i + 3];
        float x0 = xl[(size_t)e0 * 64 + lane];
        float x1 = xl[(size_t)e1 * 64 + lane];
        float x2 = xl[(size_t)e2 * 64 + lane];
        float x3 = xl[(size_t)e3 * 64 + lane];
        float p0 = atv * lrelu(x0 + xrv);
        float p1 = atv * lrelu(x1 + xrv);
        float p2 = atv * lrelu(x2 + xrv);
        float p3 = atv * lrelu(x3 + xrv);
        #pragma unroll
        for (int d = 1; d < 64; d <<= 1) {
            p0 += __shfl_xor(p0, d); p1 += __shfl_xor(p1, d);
            p2 += __shfl_xor(p2, d); p3 += __shfl_xor(p3, d);
        }
        GAT_UPD(p0, x0, m, s, acc);
        GAT_UPD(p1, x1, m, s, acc);
        GAT_UPD(p2, x2, m, s, acc);
        GAT_UPD(p3, x3, m, s, acc);
    }
    for (; i < end; ++i) {
        int src = ssrc[i];
        float xv = xl[(size_t)src * 64 + lane];
        float p = atv * lrelu(xv + xrv);
        #pragma unroll
        for (int d = 1; d < 64; d <<= 1) p += __shfl_xor(p, d);
        GAT_UPD(p, xv, m, s, acc);
    }
    float o = acc / (s + 1e-16f) + bias[lane];
    float tsum = o;
    #pragma unroll
    for (int d = 1; d < 64; d <<= 1) tsum += __shfl_xor(tsum, d);
    float mu = tsum * (1.f / 64.f);
    float dd = o - mu;
    float vsum = dd * dd;
    #pragma unroll
    for (int d = 1; d < 64; d <<= 1) vsum += __shfl_xor(vsum, d);
    float rs = rsqrtf(vsum * (1.f / 64.f) + 1e-5f);
    out[(size_t)node * 64 + lane] = dd * rs * gamma[lane] + beta[lane];
}

extern "C" void kernel_launch(void* const* d_in, const int* in_sizes, int n_in,
                              void* d_out, int out_size, void* d_ws, size_t ws_size,
                              hipStream_t stream) {
    const float* x = (const float*)d_in[0];
    const int* ei = (const int*)d_in[1];
    const float* Wl1 = (const float*)d_in[2];
    const float* Wr1 = (const float*)d_in[3];
    const float* att1 = (const float*)d_in[4];
    const float* bias1 = (const float*)d_in[5];
    const float* g1 = (const float*)d_in[6];
    const float* b1 = (const float*)d_in[7];
    const float* Wl2 = (const float*)d_in[8];
    const float* Wr2 = (const float*)d_in[9];
    const float* att2 = (const float*)d_in[10];
    const float* bias2 = (const float*)d_in[11];
    const float* g2 = (const float*)d_in[12];
    const float* b2 = (const float*)d_in[13];
    float* out = (float*)d_out;

    const int N = in_sizes[0] / 128;
    const int E = in_sizes[1] / 2;
    const int* src = ei;
    const int* dstp = ei + E;

    char* p = (char*)d_ws;
    auto alloc = [&](size_t bytes) -> char* {
        char* r = p;
        p += (bytes + 255) & ~(size_t)255;
        return r;
    };
    int* deg = (int*)alloc((size_t)N * 4);
    int* cursor = (int*)alloc((size_t)N * 4);
    int* off = (int*)alloc((size_t)(N + 1) * 4);
    int* ssrc = (int*)alloc((size_t)E * 4);
    float* bufA = (float*)alloc((size_t)N * 128 * 4);
    float* bufB = (float*)alloc((size_t)N * 128 * 4);
    float* h1 = (float*)alloc((size_t)N * 128 * 4);

    hipMemsetAsync(deg, 0, (size_t)N * 4, stream);
    hipMemsetAsync(cursor, 0, (size_t)N * 4, stream);
    degree_kernel<<<(E + 255) / 256, 256, 0, stream>>>(dstp, deg, E);
    scan_kernel<<<1, 1024, 0, stream>>>(deg, off, N);
    scatter_kernel<<<(E + 255) / 256, 256, 0, stream>>>(src, dstp, off, cursor, ssrc, E);

    dual_gemm_kernel<128><<<(N + 31) / 32, 256, 0, stream>>>(x, Wl1, Wr1, bufA, bufB, N);
    gat1_kernel<<<(N + 3) / 4, 256, 0, stream>>>(bufA, bufB, off, ssrc, att1, bias1, g1, b1, h1, N);
    dual_gemm_kernel<64><<<(N + 31) / 32, 256, 0, stream>>>(h1, Wl2, Wr2, bufA, bufB, N);
    gat2_kernel<<<(N + 3) / 4, 256, 0, stream>>>(bufA, bufB, off, ssrc, att2, bias2, g2, b2, out, N);
}

// Round 3
// 390.495 us; speedup vs baseline: 1.3682x; 1.1183x over previous
//
#include <hip/hip_runtime.h>
#include <hip/hip_bf16.h>
#include <math.h>

__device__ __forceinline__ float lrelu(float x) { return fmaxf(x, 0.2f * x); }
__device__ __forceinline__ float bflo(unsigned u) { return __uint_as_float(u << 16); }
__device__ __forceinline__ float bfhi(unsigned u) { return __uint_as_float(u & 0xffff0000u); }

// ---------------- CSR build (sort edges by dst) ----------------
__global__ void degree_kernel(const int* __restrict__ dst, int* __restrict__ deg, int E) {
    int e = blockIdx.x * blockDim.x + threadIdx.x;
    if (e < E) atomicAdd(&deg[dst[e]], 1);
}

__global__ __launch_bounds__(1024) void scan_kernel(const int* __restrict__ deg,
                                                    int* __restrict__ off, int n) {
    __shared__ int wsum[16];
    __shared__ int s_carry;
    int t = threadIdx.x, lane = t & 63, w = t >> 6;
    if (t == 0) s_carry = 0;
    __syncthreads();
    for (int base = 0; base < n; base += 4096) {
        int i = base + t * 4;
        int4 v = make_int4(0, 0, 0, 0);
        if (i + 3 < n) v = *reinterpret_cast<const int4*>(&deg[i]);
        else {
            if (i < n) v.x = deg[i];
            if (i + 1 < n) v.y = deg[i + 1];
            if (i + 2 < n) v.z = deg[i + 2];
        }
        int tsum = v.x + v.y + v.z + v.w;
        int x = tsum;
        #pragma unroll
        for (int d = 1; d < 64; d <<= 1) { int y = __shfl_up(x, d); if (lane >= d) x += y; }
        if (lane == 63) wsum[w] = x;
        __syncthreads();
        if (w == 0 && lane < 16) {
            int y = wsum[lane];
            #pragma unroll
            for (int d = 1; d < 16; d <<= 1) { int z = __shfl_up(y, d); if (lane >= d) y += z; }
            wsum[lane] = y;
        }
        __syncthreads();
        int excl = s_carry + ((w == 0) ? 0 : wsum[w - 1]) + (x - tsum);
        if (i < n) off[i] = excl;
        if (i + 1 < n) off[i + 1] = excl + v.x;
        if (i + 2 < n) off[i + 2] = excl + v.x + v.y;
        if (i + 3 < n) off[i + 3] = excl + v.x + v.y + v.z;
        __syncthreads();
        if (t == 0) s_carry += wsum[15];
        __syncthreads();
    }
    if (t == 0) off[n] = s_carry;
}

__global__ void scatter_kernel(const int* __restrict__ src, const int* __restrict__ dst,
                               const int* __restrict__ off, int* __restrict__ cursor,
                               int* __restrict__ ssrc, int E) {
    int e = blockIdx.x * blockDim.x + threadIdx.x;
    if (e < E) {
        int d = dst[e];
        int pos = off[d] + atomicAdd(&cursor[d], 1);
        ssrc[pos] = src[e];
    }
}

// ---------------- dual GEMM: Cl = A@Wl, Cr = A@Wr (K=128), bf16 outputs ----------------
template <int M>
__global__ __launch_bounds__(256) void dual_gemm_kernel(
    const float* __restrict__ A, const float* __restrict__ Wl, const float* __restrict__ Wr,
    __hip_bfloat16* __restrict__ Cl, __hip_bfloat16* __restrict__ Cr, int nrows) {
    constexpr int K = 128;
    constexpr int ROWS = 32;
    constexpr int CPT = (2 * M) / 32;  // 8 (M=128) or 4 (M=64)
    constexpr int LDR = 36;            // k-major [K][ROWS+4]
    __shared__ float As[K * LDR];
    int t = threadIdx.x;
    int row_base = blockIdx.x * ROWS;
    for (int idx = t * 4; idx < ROWS * K; idx += 1024) {
        int r = idx >> 7;
        int k = idx & 127;
        float4 v = make_float4(0.f, 0.f, 0.f, 0.f);
        if (row_base + r < nrows)
            v = *reinterpret_cast<const float4*>(&A[(size_t)(row_base + r) * K + k]);
        As[(k + 0) * LDR + r] = v.x;
        As[(k + 1) * LDR + r] = v.y;
        As[(k + 2) * LDR + r] = v.z;
        As[(k + 3) * LDR + r] = v.w;
    }
    __syncthreads();
    int cg = t & 31;
    int rg = t >> 5;
    int g0 = cg * CPT;
    const float* W = (g0 < M) ? Wl : Wr;
    __hip_bfloat16* C = (g0 < M) ? Cl : Cr;
    int c0 = (g0 < M) ? g0 : g0 - M;
    int r0 = rg * 4;
    float acc[4][CPT];
    #pragma unroll
    for (int r = 0; r < 4; ++r)
        #pragma unroll
        for (int j = 0; j < CPT; ++j) acc[r][j] = 0.f;
    #pragma unroll 4
    for (int k = 0; k < K; ++k) {
        float4 a = *reinterpret_cast<const float4*>(&As[k * LDR + r0]);
        float wv[CPT];
        #pragma unroll
        for (int j = 0; j < CPT; j += 4) {
            float4 wq = *reinterpret_cast<const float4*>(&W[(size_t)k * M + c0 + j]);
            wv[j] = wq.x; wv[j + 1] = wq.y; wv[j + 2] = wq.z; wv[j + 3] = wq.w;
        }
        #pragma unroll
        for (int j = 0; j < CPT; ++j) {
            acc[0][j] += a.x * wv[j];
            acc[1][j] += a.y * wv[j];
            acc[2][j] += a.z * wv[j];
            acc[3][j] += a.w * wv[j];
        }
    }
    #pragma unroll
    for (int r = 0; r < 4; ++r) {
        int row = row_base + r0 + r;
        if (row < nrows) {
            #pragma unroll
            for (int j = 0; j < CPT; j += 4) {
                union { ushort4 u4; __hip_bfloat16 h[4]; } cv;
                cv.h[0] = __float2bfloat16(acc[r][j + 0]);
                cv.h[1] = __float2bfloat16(acc[r][j + 1]);
                cv.h[2] = __float2bfloat16(acc[r][j + 2]);
                cv.h[3] = __float2bfloat16(acc[r][j + 3]);
                *reinterpret_cast<ushort4*>(&C[(size_t)row * M + c0 + j]) = cv.u4;
            }
        }
    }
}

// ---------------- GAT layer 1: H=8,C=16; lane->same-head feature pair ----------------
// lane l: head h = l>>3, features i0 = h*16 + 2*(l&7), i0+1. One packed bf16x2
// gather per edge, 3-stage 8-lane reduce, single exp (fixed-max softmax).
__global__ __launch_bounds__(256) void gat1_kernel(
    const __hip_bfloat16* __restrict__ xl, const __hip_bfloat16* __restrict__ xr,
    const int* __restrict__ off, const int* __restrict__ ssrc,
    const float* __restrict__ att, const float* __restrict__ bias,
    const float* __restrict__ gamma, const float* __restrict__ beta,
    float* __restrict__ out, int n) {
    int lane = threadIdx.x & 63;
    int node = blockIdx.x * 4 + (threadIdx.x >> 6);
    if (node >= n) return;
    int h = lane >> 3;
    int i0 = h * 16 + ((lane & 7) << 1);
    unsigned uxr = *reinterpret_cast<const unsigned*>(xr + (size_t)node * 128 + i0);
    float xr0 = bflo(uxr), xr1 = bfhi(uxr);
    float at0 = att[i0], at1 = att[i0 + 1];
    float s = 0.f, acc0 = 0.f, acc1 = 0.f;
    int beg = off[node], end = off[node + 1];
    int i = beg;
    for (; i + 4 <= end; i += 4) {
        int e0 = ssrc[i], e1 = ssrc[i + 1], e2 = ssrc[i + 2], e3 = ssrc[i + 3];
        unsigned u0 = *reinterpret_cast<const unsigned*>(xl + (size_t)e0 * 128 + i0);
        unsigned u1 = *reinterpret_cast<const unsigned*>(xl + (size_t)e1 * 128 + i0);
        unsigned u2 = *reinterpret_cast<const unsigned*>(xl + (size_t)e2 * 128 + i0);
        unsigned u3 = *reinterpret_cast<const unsigned*>(xl + (size_t)e3 * 128 + i0);
        float x00 = bflo(u0), x01 = bfhi(u0);
        float x10 = bflo(u1), x11 = bfhi(u1);
        float x20 = bflo(u2), x21 = bfhi(u2);
        float x30 = bflo(u3), x31 = bfhi(u3);
        float p0 = at0 * lrelu(x00 + xr0) + at1 * lrelu(x01 + xr1);
        float p1 = at0 * lrelu(x10 + xr0) + at1 * lrelu(x11 + xr1);
        float p2 = at0 * lrelu(x20 + xr0) + at1 * lrelu(x21 + xr1);
        float p3 = at0 * lrelu(x30 + xr0) + at1 * lrelu(x31 + xr1);
        #pragma unroll
        for (int d = 1; d < 8; d <<= 1) {
            p0 += __shfl_xor(p0, d); p1 += __shfl_xor(p1, d);
            p2 += __shfl_xor(p2, d); p3 += __shfl_xor(p3, d);
        }
        float w0 = __expf(fminf(p0, 60.f));
        float w1 = __expf(fminf(p1, 60.f));
        float w2 = __expf(fminf(p2, 60.f));
        float w3 = __expf(fminf(p3, 60.f));
        s += (w0 + w1) + (w2 + w3);
        acc0 += w0 * x00 + w1 * x10 + w2 * x20 + w3 * x30;
        acc1 += w0 * x01 + w1 * x11 + w2 * x21 + w3 * x31;
    }
    for (; i < end; ++i) {
        int e = ssrc[i];
        unsigned u = *reinterpret_cast<const unsigned*>(xl + (size_t)e * 128 + i0);
        float x0 = bflo(u), x1 = bfhi(u);
        float p = at0 * lrelu(x0 + xr0) + at1 * lrelu(x1 + xr1);
        #pragma unroll
        for (int d = 1; d < 8; d <<= 1) p += __shfl_xor(p, d);
        float w = __expf(fminf(p, 60.f));
        s += w; acc0 += w * x0; acc1 += w * x1;
    }
    float inv = 1.f / (s + 1e-16f);
    float o0 = acc0 * inv + bias[i0];
    float o1 = acc1 * inv + bias[i0 + 1];
    // LayerNorm over 128 + ELU
    float tsum = o0 + o1;
    #pragma unroll
    for (int d = 1; d < 64; d <<= 1) tsum += __shfl_xor(tsum, d);
    float mu = tsum * (1.f / 128.f);
    float d0 = o0 - mu, d1 = o1 - mu;
    float vsum = d0 * d0 + d1 * d1;
    #pragma unroll
    for (int d = 1; d < 64; d <<= 1) vsum += __shfl_xor(vsum, d);
    float rs = rsqrtf(vsum * (1.f / 128.f) + 1e-5f);
    float y0 = d0 * rs * gamma[i0] + beta[i0];
    float y1 = d1 * rs * gamma[i0 + 1] + beta[i0 + 1];
    y0 = y0 > 0.f ? y0 : expm1f(y0);
    y1 = y1 > 0.f ? y1 : expm1f(y1);
    *reinterpret_cast<float2*>(out + (size_t)node * 128 + i0) = make_float2(y0, y1);
}

// ---------------- GAT layer 2: H=1,C=64; 2 edges/wave (32-lane halves) ----------------
__global__ __launch_bounds__(256) void gat2_kernel(
    const __hip_bfloat16* __restrict__ xl, const __hip_bfloat16* __restrict__ xr,
    const int* __restrict__ off, const int* __restrict__ ssrc,
    const float* __restrict__ att, const float* __restrict__ bias,
    const float* __restrict__ gamma, const float* __restrict__ beta,
    float* __restrict__ out, int n) {
    int lane = threadIdx.x & 63;
    int node = blockIdx.x * 4 + (threadIdx.x >> 6);
    if (node >= n) return;
    int half = lane >> 5;
    int c2 = (lane & 31) << 1;
    unsigned uxr = *reinterpret_cast<const unsigned*>(xr + (size_t)node * 64 + c2);
    float xr0 = bflo(uxr), xr1 = bfhi(uxr);
    float at0 = att[c2], at1 = att[c2 + 1];
    float s = 0.f, acc0 = 0.f, acc1 = 0.f;
    int beg = off[node], end = off[node + 1];
    int i = beg;
    for (; i + 4 <= end; i += 4) {
        int eA = ssrc[i + half], eB = ssrc[i + 2 + half];
        unsigned uA = *reinterpret_cast<const unsigned*>(xl + (size_t)eA * 64 + c2);
        unsigned uB = *reinterpret_cast<const unsigned*>(xl + (size_t)eB * 64 + c2);
        float xA0 = bflo(uA), xA1 = bfhi(uA);
        float xB0 = bflo(uB), xB1 = bfhi(uB);
        float pA = at0 * lrelu(xA0 + xr0) + at1 * lrelu(xA1 + xr1);
        float pB = at0 * lrelu(xB0 + xr0) + at1 * lrelu(xB1 + xr1);
        #pragma unroll
        for (int d = 1; d < 32; d <<= 1) {
            pA += __shfl_xor(pA, d); pB += __shfl_xor(pB, d);
        }
        float wA = __expf(fminf(pA, 60.f));
        float wB = __expf(fminf(pB, 60.f));
        s += wA + wB;
        acc0 += wA * xA0 + wB * xB0;
        acc1 += wA * xA1 + wB * xB1;
    }
    for (; i < end; i += 2) {
        int e = i + half;
        bool valid = e < end;
        int se = ssrc[valid ? e : i];
        unsigned u = *reinterpret_cast<const unsigned*>(xl + (size_t)se * 64 + c2);
        float x0 = bflo(u), x1 = bfhi(u);
        float p = at0 * lrelu(x0 + xr0) + at1 * lrelu(x1 + xr1);
        #pragma unroll
        for (int d = 1; d < 32; d <<= 1) p += __shfl_xor(p, d);
        float w = valid ? __expf(fminf(p, 60.f)) : 0.f;
        s += w; acc0 += w * x0; acc1 += w * x1;
    }
    // combine the two half-wave partial sums
    s += __shfl_xor(s, 32);
    acc0 += __shfl_xor(acc0, 32);
    acc1 += __shfl_xor(acc1, 32);
    float inv = 1.f / (s + 1e-16f);
    float o0 = acc0 * inv + bias[c2];
    float o1 = acc1 * inv + bias[c2 + 1];
    // LayerNorm over 64 (features live in 32 lanes, replicated across halves)
    float tsum = o0 + o1;
    #pragma unroll
    for (int d = 1; d < 32; d <<= 1) tsum += __shfl_xor(tsum, d);
    float mu = tsum * (1.f / 64.f);
    float d0 = o0 - mu, d1 = o1 - mu;
    float vsum = d0 * d0 + d1 * d1;
    #pragma unroll
    for (int d = 1; d < 32; d <<= 1) vsum += __shfl_xor(vsum, d);
    float rs = rsqrtf(vsum * (1.f / 64.f) + 1e-5f);
    if (half == 0) {
        float y0 = d0 * rs * gamma[c2] + beta[c2];
        float y1 = d1 * rs * gamma[c2 + 1] + beta[c2 + 1];
        *reinterpret_cast<float2*>(out + (size_t)node * 64 + c2) = make_float2(y0, y1);
    }
}

extern "C" void kernel_launch(void* const* d_in, const int* in_sizes, int n_in,
                              void* d_out, int out_size, void* d_ws, size_t ws_size,
                              hipStream_t stream) {
    const float* x = (const float*)d_in[0];
    const int* ei = (const int*)d_in[1];
    const float* Wl1 = (const float*)d_in[2];
    const float* Wr1 = (const float*)d_in[3];
    const float* att1 = (const float*)d_in[4];
    const float* bias1 = (const float*)d_in[5];
    const float* g1 = (const float*)d_in[6];
    const float* b1 = (const float*)d_in[7];
    const float* Wl2 = (const float*)d_in[8];
    const float* Wr2 = (const float*)d_in[9];
    const float* att2 = (const float*)d_in[10];
    const float* bias2 = (const float*)d_in[11];
    const float* g2 = (const float*)d_in[12];
    const float* b2 = (const float*)d_in[13];
    float* out = (float*)d_out;

    const int N = in_sizes[0] / 128;
    const int E = in_sizes[1] / 2;
    const int* src = ei;
    const int* dstp = ei + E;

    char* p = (char*)d_ws;
    auto alloc = [&](size_t bytes) -> char* {
        char* r = p;
        p += (bytes + 255) & ~(size_t)255;
        return r;
    };
    int* deg = (int*)alloc((size_t)N * 4);
    int* cursor = (int*)alloc((size_t)N * 4);
    int* off = (int*)alloc((size_t)(N + 1) * 4);
    int* ssrc = (int*)alloc((size_t)E * 4);
    __hip_bfloat16* bufA = (__hip_bfloat16*)alloc((size_t)N * 128 * 2);  // xl (bf16)
    __hip_bfloat16* bufB = (__hip_bfloat16*)alloc((size_t)N * 128 * 2);  // xr (bf16)
    float* h1 = (float*)alloc((size_t)N * 128 * 4);

    hipMemsetAsync(deg, 0, (size_t)N * 4, stream);
    hipMemsetAsync(cursor, 0, (size_t)N * 4, stream);
    degree_kernel<<<(E + 255) / 256, 256, 0, stream>>>(dstp, deg, E);
    scan_kernel<<<1, 1024, 0, stream>>>(deg, off, N);
    scatter_kernel<<<(E + 255) / 256, 256, 0, stream>>>(src, dstp, off, cursor, ssrc, E);

    dual_gemm_kernel<128><<<(N + 31) / 32, 256, 0, stream>>>(x, Wl1, Wr1, bufA, bufB, N);
    gat1_kernel<<<(N + 3) / 4, 256, 0, stream>>>(bufA, bufB, off, ssrc, att1, bias1, g1, b1, h1, N);
    dual_gemm_kernel<64><<<(N + 31) / 32, 256, 0, stream>>>(h1, Wl2, Wr2, bufA, bufB, N);
    gat2_kernel<<<(N + 3) / 4, 256, 0, stream>>>(bufA, bufB, off, ssrc, att2, bias2, g2, b2, out, N);
}

// Round 5
// 321.683 us; speedup vs baseline: 1.6609x; 1.2139x over previous
//
#include <hip/hip_runtime.h>
#include <hip/hip_bf16.h>
#include <math.h>

typedef short s16x8 __attribute__((ext_vector_type(8)));
typedef float f32x4 __attribute__((ext_vector_type(4)));

__device__ __forceinline__ float lrelu(float x) { return fmaxf(x, 0.2f * x); }
__device__ __forceinline__ float bflo(unsigned u) { return __uint_as_float(u << 16); }
__device__ __forceinline__ float bfhi(unsigned u) { return __uint_as_float(u & 0xffff0000u); }
__device__ __forceinline__ unsigned short f2bf(float f) {
    __hip_bfloat16 h = __float2bfloat16(f);
    return __builtin_bit_cast(unsigned short, h);
}
__device__ __forceinline__ f32x4 mfma_bf16(s16x8 a, s16x8 b, f32x4 c) {
    asm("v_mfma_f32_16x16x32_bf16 %0, %1, %2, %0" : "+v"(c) : "v"(a), "v"(b));
    return c;
}

// ---------------- CSR build (sort edges by dst) ----------------
__global__ void degree_kernel(const int* __restrict__ dst, int* __restrict__ deg, int E) {
    int e = blockIdx.x * blockDim.x + threadIdx.x;
    if (e < E) atomicAdd(&deg[dst[e]], 1);
}

__global__ __launch_bounds__(1024) void scan_kernel(const int* __restrict__ deg,
                                                    int* __restrict__ off, int n) {
    __shared__ int wsum[16];
    __shared__ int s_carry;
    int t = threadIdx.x, lane = t & 63, w = t >> 6;
    if (t == 0) s_carry = 0;
    __syncthreads();
    for (int base = 0; base < n; base += 4096) {
        int i = base + t * 4;
        int4 v = make_int4(0, 0, 0, 0);
        if (i + 3 < n) v = *reinterpret_cast<const int4*>(&deg[i]);
        else {
            if (i < n) v.x = deg[i];
            if (i + 1 < n) v.y = deg[i + 1];
            if (i + 2 < n) v.z = deg[i + 2];
        }
        int tsum = v.x + v.y + v.z + v.w;
        int x = tsum;
        #pragma unroll
        for (int d = 1; d < 64; d <<= 1) { int y = __shfl_up(x, d); if (lane >= d) x += y; }
        if (lane == 63) wsum[w] = x;
        __syncthreads();
        if (w == 0 && lane < 16) {
            int y = wsum[lane];
            #pragma unroll
            for (int d = 1; d < 16; d <<= 1) { int z = __shfl_up(y, d); if (lane >= d) y += z; }
            wsum[lane] = y;
        }
        __syncthreads();
        int excl = s_carry + ((w == 0) ? 0 : wsum[w - 1]) + (x - tsum);
        if (i < n) off[i] = excl;
        if (i + 1 < n) off[i + 1] = excl + v.x;
        if (i + 2 < n) off[i + 2] = excl + v.x + v.y;
        if (i + 3 < n) off[i + 3] = excl + v.x + v.y + v.z;
        __syncthreads();
        if (t == 0) s_carry += wsum[15];
        __syncthreads();
    }
    if (t == 0) off[n] = s_carry;
}

__global__ void scatter_kernel(const int* __restrict__ src, const int* __restrict__ dst,
                               const int* __restrict__ off, int* __restrict__ cursor,
                               int* __restrict__ ssrc, int E) {
    int e = blockIdx.x * blockDim.x + threadIdx.x;
    if (e < E) {
        int d = dst[e];
        int pos = off[d] + atomicAdd(&cursor[d], 1);
        ssrc[pos] = src[e];
    }
}

// ---------------- weight prep: Wt[n][k] bf16, n-concat of Wl|Wr cols ----------------
__global__ void wt_prep_kernel(const float* __restrict__ Wl, const float* __restrict__ Wr,
                               unsigned short* __restrict__ Wt, int NOUT, int HALF) {
    int idx = blockIdx.x * 256 + threadIdx.x;  // idx = n*128 + k
    if (idx < NOUT * 128) {
        int n = idx >> 7, k = idx & 127;
        float v = (n < HALF) ? Wl[k * HALF + n] : Wr[k * HALF + (n - HALF)];
        Wt[idx] = f2bf(v);
    }
}

// ---------------- MFMA dual GEMM: C = A(bf16/f32,[*,128]) @ Wt^T, bf16 out ----------------
// Block: 4 waves, 64 rows x NOUT cols. A staged in LDS (XOR-swizzled 16B units).
// Frags: A row=lane&15, k-slot=(lane>>4); B col=lane&15, same k-slot (mapping cancels).
// C/D: col=lane&15, row=(lane>>4)*4+i  [m89-verified].
template <int NOUT, bool AFP32>
__global__ __launch_bounds__(256) void mfma_gemm_kernel(
    const void* __restrict__ A, const unsigned short* __restrict__ Wt,
    unsigned short* __restrict__ Cl, unsigned short* __restrict__ Cr, int nrows) {
    constexpr int HALF = NOUT / 2;
    constexpr int CT = NOUT / 64;  // col-tiles per wave
    __shared__ unsigned short As[64 * 128];
    int t = threadIdx.x, lane = t & 63, wave = t >> 6;
    int row_base = blockIdx.x * 64;
    int rows_here = nrows - row_base;  // >=64 except last block
    // stage A -> LDS, swizzled: unit su = r*16 + (c8 ^ (r&7))
    #pragma unroll
    for (int it = 0; it < 4; ++it) {
        int q = it * 256 + t;
        int r = q >> 4, c8 = q & 15;
        int su = r * 16 + (c8 ^ (r & 7));
        s16x8 v = {0, 0, 0, 0, 0, 0, 0, 0};
        if (r < rows_here) {
            if (AFP32) {
                const float4* g = reinterpret_cast<const float4*>(
                    (const float*)A + ((size_t)(row_base + r)) * 128 + c8 * 8);
                float4 v0 = g[0], v1 = g[1];
                union { s16x8 s; unsigned short u[8]; } pk;
                pk.u[0] = f2bf(v0.x); pk.u[1] = f2bf(v0.y);
                pk.u[2] = f2bf(v0.z); pk.u[3] = f2bf(v0.w);
                pk.u[4] = f2bf(v1.x); pk.u[5] = f2bf(v1.y);
                pk.u[6] = f2bf(v1.z); pk.u[7] = f2bf(v1.w);
                v = pk.s;
            } else {
                v = *reinterpret_cast<const s16x8*>(
                    (const unsigned short*)A + ((size_t)(row_base + r)) * 128 + c8 * 8);
            }
        }
        reinterpret_cast<s16x8*>(As)[su] = v;
    }
    __syncthreads();
    int m16 = lane & 15, kg = lane >> 4;
    int colw = wave * (NOUT / 4);
    // B fragments: register-resident (Wt is L1/L2-hot)
    s16x8 bfr[CT][4];
    const s16x8* Wt16 = reinterpret_cast<const s16x8*>(Wt);
    #pragma unroll
    for (int ct = 0; ct < CT; ++ct)
        #pragma unroll
        for (int ks = 0; ks < 4; ++ks)
            bfr[ct][ks] = Wt16[(size_t)(colw + ct * 16 + m16) * 16 + ks * 4 + kg];
    f32x4 acc[4][CT];
    #pragma unroll
    for (int rt = 0; rt < 4; ++rt)
        #pragma unroll
        for (int ct = 0; ct < CT; ++ct) acc[rt][ct] = (f32x4){0.f, 0.f, 0.f, 0.f};
    const s16x8* As16 = reinterpret_cast<const s16x8*>(As);
    int sw = m16 & 7;
    #pragma unroll
    for (int rt = 0; rt < 4; ++rt) {
        int abase = (rt * 16 + m16) * 16;
        #pragma unroll
        for (int ks = 0; ks < 4; ++ks) {
            s16x8 af = As16[abase + ((ks * 4 + kg) ^ sw)];
            #pragma unroll
            for (int ct = 0; ct < CT; ++ct)
                acc[rt][ct] = mfma_bf16(af, bfr[ct][ks], acc[rt][ct]);
        }
    }
    // epilogue: D col = colw+ct*16+m16, row = row_base+rt*16+kg*4+i
    int rq = kg * 4;
    #pragma unroll
    for (int rt = 0; rt < 4; ++rt) {
        #pragma unroll
        for (int ct = 0; ct < CT; ++ct) {
            int n = colw + ct * 16 + m16;
            unsigned short* Cp = (n < HALF) ? (Cl + n) : (Cr + (n - HALF));
            int row0 = row_base + rt * 16 + rq;
            #pragma unroll
            for (int i = 0; i < 4; ++i) {
                int row = row0 + i;
                if (row < nrows) Cp[(size_t)row * HALF] = f2bf(acc[rt][ct][i]);
            }
        }
    }
}

// ---------------- GAT layer 1: H=8,C=16; bf16 h1 output ----------------
__global__ __launch_bounds__(256) void gat1_kernel(
    const __hip_bfloat16* __restrict__ xl, const __hip_bfloat16* __restrict__ xr,
    const int* __restrict__ off, const int* __restrict__ ssrc,
    const float* __restrict__ att, const float* __restrict__ bias,
    const float* __restrict__ gamma, const float* __restrict__ beta,
    unsigned short* __restrict__ out, int n) {
    int lane = threadIdx.x & 63;
    int node = blockIdx.x * 4 + (threadIdx.x >> 6);
    if (node >= n) return;
    int h = lane >> 3;
    int i0 = h * 16 + ((lane & 7) << 1);
    unsigned uxr = *reinterpret_cast<const unsigned*>(xr + (size_t)node * 128 + i0);
    float xr0 = bflo(uxr), xr1 = bfhi(uxr);
    float at0 = att[i0], at1 = att[i0 + 1];
    float s = 0.f, acc0 = 0.f, acc1 = 0.f;
    int beg = off[node], end = off[node + 1];
    int i = beg;
    for (; i + 4 <= end; i += 4) {
        int e0 = ssrc[i], e1 = ssrc[i + 1], e2 = ssrc[i + 2], e3 = ssrc[i + 3];
        unsigned u0 = *reinterpret_cast<const unsigned*>(xl + (size_t)e0 * 128 + i0);
        unsigned u1 = *reinterpret_cast<const unsigned*>(xl + (size_t)e1 * 128 + i0);
        unsigned u2 = *reinterpret_cast<const unsigned*>(xl + (size_t)e2 * 128 + i0);
        unsigned u3 = *reinterpret_cast<const unsigned*>(xl + (size_t)e3 * 128 + i0);
        float x00 = bflo(u0), x01 = bfhi(u0);
        float x10 = bflo(u1), x11 = bfhi(u1);
        float x20 = bflo(u2), x21 = bfhi(u2);
        float x30 = bflo(u3), x31 = bfhi(u3);
        float p0 = at0 * lrelu(x00 + xr0) + at1 * lrelu(x01 + xr1);
        float p1 = at0 * lrelu(x10 + xr0) + at1 * lrelu(x11 + xr1);
        float p2 = at0 * lrelu(x20 + xr0) + at1 * lrelu(x21 + xr1);
        float p3 = at0 * lrelu(x30 + xr0) + at1 * lrelu(x31 + xr1);
        #pragma unroll
        for (int d = 1; d < 8; d <<= 1) {
            p0 += __shfl_xor(p0, d); p1 += __shfl_xor(p1, d);
            p2 += __shfl_xor(p2, d); p3 += __shfl_xor(p3, d);
        }
        float w0 = __expf(fminf(p0, 60.f));
        float w1 = __expf(fminf(p1, 60.f));
        float w2 = __expf(fminf(p2, 60.f));
        float w3 = __expf(fminf(p3, 60.f));
        s += (w0 + w1) + (w2 + w3);
        acc0 += w0 * x00 + w1 * x10 + w2 * x20 + w3 * x30;
        acc1 += w0 * x01 + w1 * x11 + w2 * x21 + w3 * x31;
    }
    for (; i < end; ++i) {
        int e = ssrc[i];
        unsigned u = *reinterpret_cast<const unsigned*>(xl + (size_t)e * 128 + i0);
        float x0 = bflo(u), x1 = bfhi(u);
        float p = at0 * lrelu(x0 + xr0) + at1 * lrelu(x1 + xr1);
        #pragma unroll
        for (int d = 1; d < 8; d <<= 1) p += __shfl_xor(p, d);
        float w = __expf(fminf(p, 60.f));
        s += w; acc0 += w * x0; acc1 += w * x1;
    }
    float inv = 1.f / (s + 1e-16f);
    float o0 = acc0 * inv + bias[i0];
    float o1 = acc1 * inv + bias[i0 + 1];
    float tsum = o0 + o1;
    #pragma unroll
    for (int d = 1; d < 64; d <<= 1) tsum += __shfl_xor(tsum, d);
    float mu = tsum * (1.f / 128.f);
    float d0 = o0 - mu, d1 = o1 - mu;
    float vsum = d0 * d0 + d1 * d1;
    #pragma unroll
    for (int d = 1; d < 64; d <<= 1) vsum += __shfl_xor(vsum, d);
    float rs = rsqrtf(vsum * (1.f / 128.f) + 1e-5f);
    float y0 = d0 * rs * gamma[i0] + beta[i0];
    float y1 = d1 * rs * gamma[i0 + 1] + beta[i0 + 1];
    y0 = y0 > 0.f ? y0 : expm1f(y0);
    y1 = y1 > 0.f ? y1 : expm1f(y1);
    unsigned pk = (unsigned)f2bf(y0) | ((unsigned)f2bf(y1) << 16);
    *reinterpret_cast<unsigned*>(out + (size_t)node * 128 + i0) = pk;
}

// ---------------- GAT layer 2: H=1,C=64; 2 edges/wave halves; fp32 out ----------------
__global__ __launch_bounds__(256) void gat2_kernel(
    const __hip_bfloat16* __restrict__ xl, const __hip_bfloat16* __restrict__ xr,
    const int* __restrict__ off, const int* __restrict__ ssrc,
    const float* __restrict__ att, const float* __restrict__ bias,
    const float* __restrict__ gamma, const float* __restrict__ beta,
    float* __restrict__ out, int n) {
    int lane = threadIdx.x & 63;
    int node = blockIdx.x * 4 + (threadIdx.x >> 6);
    if (node >= n) return;
    int half = lane >> 5;
    int c2 = (lane & 31) << 1;
    unsigned uxr = *reinterpret_cast<const unsigned*>(xr + (size_t)node * 64 + c2);
    float xr0 = bflo(uxr), xr1 = bfhi(uxr);
    float at0 = att[c2], at1 = att[c2 + 1];
    float s = 0.f, acc0 = 0.f, acc1 = 0.f;
    int beg = off[node], end = off[node + 1];
    int i = beg;
    for (; i + 4 <= end; i += 4) {
        int eA = ssrc[i + half], eB = ssrc[i + 2 + half];
        unsigned uA = *reinterpret_cast<const unsigned*>(xl + (size_t)eA * 64 + c2);
        unsigned uB = *reinterpret_cast<const unsigned*>(xl + (size_t)eB * 64 + c2);
        float xA0 = bflo(uA), xA1 = bfhi(uA);
        float xB0 = bflo(uB), xB1 = bfhi(uB);
        float pA = at0 * lrelu(xA0 + xr0) + at1 * lrelu(xA1 + xr1);
        float pB = at0 * lrelu(xB0 + xr0) + at1 * lrelu(xB1 + xr1);
        #pragma unroll
        for (int d = 1; d < 32; d <<= 1) {
            pA += __shfl_xor(pA, d); pB += __shfl_xor(pB, d);
        }
        float wA = __expf(fminf(pA, 60.f));
        float wB = __expf(fminf(pB, 60.f));
        s += wA + wB;
        acc0 += wA * xA0 + wB * xB0;
        acc1 += wA * xA1 + wB * xB1;
    }
    for (; i < end; i += 2) {
        int e = i + half;
        bool valid = e < end;
        int se = ssrc[valid ? e : i];
        unsigned u = *reinterpret_cast<const unsigned*>(xl + (size_t)se * 64 + c2);
        float x0 = bflo(u), x1 = bfhi(u);
        float p = at0 * lrelu(x0 + xr0) + at1 * lrelu(x1 + xr1);
        #pragma unroll
        for (int d = 1; d < 32; d <<= 1) p += __shfl_xor(p, d);
        float w = valid ? __expf(fminf(p, 60.f)) : 0.f;
        s += w; acc0 += w * x0; acc1 += w * x1;
    }
    s += __shfl_xor(s, 32);
    acc0 += __shfl_xor(acc0, 32);
    acc1 += __shfl_xor(acc1, 32);
    float inv = 1.f / (s + 1e-16f);
    float o0 = acc0 * inv + bias[c2];
    float o1 = acc1 * inv + bias[c2 + 1];
    float tsum = o0 + o1;
    #pragma unroll
    for (int d = 1; d < 32; d <<= 1) tsum += __shfl_xor(tsum, d);
    float mu = tsum * (1.f / 64.f);
    float d0 = o0 - mu, d1 = o1 - mu;
    float vsum = d0 * d0 + d1 * d1;
    #pragma unroll
    for (int d = 1; d < 32; d <<= 1) vsum += __shfl_xor(vsum, d);
    float rs = rsqrtf(vsum * (1.f / 64.f) + 1e-5f);
    if (half == 0) {
        float y0 = d0 * rs * gamma[c2] + beta[c2];
        float y1 = d1 * rs * gamma[c2 + 1] + beta[c2 + 1];
        *reinterpret_cast<float2*>(out + (size_t)node * 64 + c2) = make_float2(y0, y1);
    }
}

extern "C" void kernel_launch(void* const* d_in, const int* in_sizes, int n_in,
                              void* d_out, int out_size, void* d_ws, size_t ws_size,
                              hipStream_t stream) {
    const float* x = (const float*)d_in[0];
    const int* ei = (const int*)d_in[1];
    const float* Wl1 = (const float*)d_in[2];
    const float* Wr1 = (const float*)d_in[3];
    const float* att1 = (const float*)d_in[4];
    const float* bias1 = (const float*)d_in[5];
    const float* g1 = (const float*)d_in[6];
    const float* b1 = (const float*)d_in[7];
    const float* Wl2 = (const float*)d_in[8];
    const float* Wr2 = (const float*)d_in[9];
    const float* att2 = (const float*)d_in[10];
    const float* bias2 = (const float*)d_in[11];
    const float* g2 = (const float*)d_in[12];
    const float* b2 = (const float*)d_in[13];
    float* out = (float*)d_out;

    const int N = in_sizes[0] / 128;
    const int E = in_sizes[1] / 2;
    const int* src = ei;
    const int* dstp = ei + E;

    char* p = (char*)d_ws;
    auto alloc = [&](size_t bytes) -> char* {
        char* r = p;
        p += (bytes + 255) & ~(size_t)255;
        return r;
    };
    int* deg = (int*)alloc((size_t)N * 4);
    int* cursor = (int*)alloc((size_t)N * 4);
    int* off = (int*)alloc((size_t)(N + 1) * 4);
    int* ssrc = (int*)alloc((size_t)E * 4);
    unsigned short* Wt1 = (unsigned short*)alloc(256 * 128 * 2);
    unsigned short* Wt2 = (unsigned short*)alloc(128 * 128 * 2);
    unsigned short* bufA = (unsigned short*)alloc((size_t)N * 128 * 2);
    unsigned short* bufB = (unsigned short*)alloc((size_t)N * 128 * 2);
    unsigned short* h1u = (unsigned short*)alloc((size_t)N * 128 * 2);

    hipMemsetAsync(deg, 0, (size_t)N * 4, stream);
    hipMemsetAsync(cursor, 0, (size_t)N * 4, stream);
    degree_kernel<<<(E + 255) / 256, 256, 0, stream>>>(dstp, deg, E);
    wt_prep_kernel<<<(256 * 128 + 255) / 256, 256, 0, stream>>>(Wl1, Wr1, Wt1, 256, 128);
    wt_prep_kernel<<<(128 * 128 + 255) / 256, 256, 0, stream>>>(Wl2, Wr2, Wt2, 128, 64);
    scan_kernel<<<1, 1024, 0, stream>>>(deg, off, N);
    scatter_kernel<<<(E + 255) / 256, 256, 0, stream>>>(src, dstp, off, cursor, ssrc, E);

    int gblocks = (N + 63) / 64;
    mfma_gemm_kernel<256, true><<<gblocks, 256, 0, stream>>>(x, Wt1, bufA, bufB, N);
    gat1_kernel<<<(N + 3) / 4, 256, 0, stream>>>(
        (const __hip_bfloat16*)bufA, (const __hip_bfloat16*)bufB, off, ssrc,
        att1, bias1, g1, b1, h1u, N);
    mfma_gemm_kernel<128, false><<<gblocks, 256, 0, stream>>>(h1u, Wt2, bufA, bufB, N);
    gat2_kernel<<<(N + 3) / 4, 256, 0, stream>>>(
        (const __hip_bfloat16*)bufA, (const __hip_bfloat16*)bufB, off, ssrc,
        att2, bias2, g2, b2, out, N);
}